// Round 1
// baseline (1336.955 us; speedup 1.0000x reference)
//
#include <hip/hip_runtime.h>
#include <math.h>

// MultiHeadAttention: x[1,4096,1024] fp32, Wq/Wk/Wv[1024,1024], Wo[1024,1024].
// Outputs (concat in d_out): y[4096*1024] fp32, attn[8*4096*4096] fp32.
//
// Strategy:
//  - all GEMMs via mfma_f32_16x16x32_bf16, m97-style 128x128 tile, B^T layout
//  - split-bf16 (hi+lo, 3 mfmas) on the Q/K/logits path for fp32-level accuracy
//  - plain bf16 on V / PV / Wo path
//  - softmax without max-subtraction (logits are tiny): QK^T epilogue writes
//    exp(s) to d_out attn region + atomic rowsums; PV normalizes in staging and
//    writes the final attn back while computing y = attn @ V.
//
// Workspace layout (needs ~84.3 MiB of d_ws).

typedef unsigned short u16;
typedef __attribute__((ext_vector_type(8))) short bf16x8;
typedef __attribute__((ext_vector_type(4))) float f32x4;

#define SEQ 4096
#define FDIM 1024
#define NHEAD 8

__device__ __forceinline__ u16 f2bf(float f) {
  unsigned u = __float_as_uint(f);
  u += 0x7fffu + ((u >> 16) & 1u);   // round-to-nearest-even
  return (u16)(u >> 16);
}
__device__ __forceinline__ float bf2f(u16 h) {
  return __uint_as_float(((unsigned)h) << 16);
}

__device__ __forceinline__ void g2l16(const void* g, void* l) {
  __builtin_amdgcn_global_load_lds(
      (const __attribute__((address_space(1))) void*)g,
      (__attribute__((address_space(3))) void*)l, 16, 0, 0);
}

// ---------------------------------------------------------------- prep kernels

__global__ void split_f32_bf16(const float4* __restrict__ in, u16* __restrict__ ohi,
                               u16* __restrict__ olo, int n4) {
  int i = blockIdx.x * 256 + threadIdx.x;
  if (i >= n4) return;
  float4 v = in[i];
  u16 h0 = f2bf(v.x), h1 = f2bf(v.y), h2 = f2bf(v.z), h3 = f2bf(v.w);
  u16 l0 = f2bf(v.x - bf2f(h0)), l1 = f2bf(v.y - bf2f(h1));
  u16 l2 = f2bf(v.z - bf2f(h2)), l3 = f2bf(v.w - bf2f(h3));
  ushort4 hv = make_ushort4(h0, h1, h2, h3);
  ushort4 lv = make_ushort4(l0, l1, l2, l3);
  *(ushort4*)(ohi + 4 * (size_t)i) = hv;
  *(ushort4*)(olo + 4 * (size_t)i) = lv;
}

// out[n][k] = in[k][n], 1024x1024, optional split
__global__ void transpose_split_w(const float* __restrict__ in, u16* __restrict__ ohi,
                                  u16* __restrict__ olo, int dim, int do_split) {
  __shared__ float t[32][33];
  int tx = threadIdx.x, ty = threadIdx.y;
  int x = blockIdx.x * 32 + tx;
  int y0 = blockIdx.y * 32;
  for (int j = ty; j < 32; j += 8) t[j][tx] = in[(long)(y0 + j) * dim + x];
  __syncthreads();
  int x2 = y0 + tx;          // k
  int y2 = blockIdx.x * 32;  // n base
  for (int j = ty; j < 32; j += 8) {
    float v = t[tx][j];
    u16 hi = f2bf(v);
    ohi[(long)(y2 + j) * dim + x2] = hi;
    if (do_split) olo[(long)(y2 + j) * dim + x2] = f2bf(v - bf2f(hi));
  }
}

// out[c*rows + r] = in[r*cols + c]  (bf16)
__global__ void transpose_bf16(const u16* __restrict__ in, u16* __restrict__ out,
                               int rows, int cols) {
  __shared__ u16 t[32][33];
  int tx = threadIdx.x, ty = threadIdx.y;
  int x = blockIdx.x * 32 + tx;
  int y0 = blockIdx.y * 32;
  for (int j = ty; j < 32; j += 8) t[j][tx] = in[(long)(y0 + j) * cols + x];
  __syncthreads();
  int x2 = y0 + tx;
  int y2 = blockIdx.x * 32;
  for (int j = ty; j < 32; j += 8) out[(long)(y2 + j) * rows + x2] = t[tx][j];
}

__global__ void reciprocal_k(const float* __restrict__ in, float* __restrict__ out, int n) {
  int i = blockIdx.x * 256 + threadIdx.x;
  if (i < n) out[i] = 1.0f / in[i];
}

// ---------------------------------------------------------------- GEMM (C = A * B^T)
// A: [M,K] (bf16 hi/lo, or fp32 with on-the-fly normalize+writeback when AF32)
// B: [N,K] row-major bf16 (hi/lo when SPLIT)
// EPI: 0 = fp32 store, 1 = bf16 store, 2 = split bf16 store, 3 = exp + rowsum
template <int BK, bool SPLIT, bool AF32, int EPI>
__global__ __launch_bounds__(256, 2) void gemm_bt(
    const u16* Ahi_, const u16* Alo_,
    const float* Af32_, float* Awb_, const float* invRow_,
    const u16* Bhi_, const u16* Blo_,
    void* C0, void* C1, float* rowSum_,
    int Kdim, int lda, int ldb, int ldc,
    long aStrH, long bStrH, long cStrH, long rStrH, float scale) {
  constexpr int LDSN = 128 * BK;
  __shared__ u16 sAhi[LDSN];
  __shared__ u16 sBhi[LDSN];
  __shared__ u16 sAlo[SPLIT ? LDSN : 2];
  __shared__ u16 sBlo[SPLIT ? LDSN : 2];

  const int tid = threadIdx.x;
  const int lane = tid & 63;
  const int wave = tid >> 6;
  const int wr = wave >> 1, wc = wave & 1;
  const int quad = lane >> 4, l16 = lane & 15;
  const int h = blockIdx.z;
  const long bm = (long)blockIdx.y * 128;
  const long bn = (long)blockIdx.x * 128;

  const u16* Ahi = nullptr;
  const u16* Alo = nullptr;
  const float* Af32 = nullptr;
  float* Awb = nullptr;
  const float* invRow = nullptr;
  if constexpr (AF32) {
    Af32 = Af32_ + (long)h * aStrH;
    Awb = Awb_ + (long)h * aStrH;
    invRow = invRow_ + (long)h * rStrH;
  } else {
    Ahi = Ahi_ + (long)h * aStrH;
    if constexpr (SPLIT) Alo = Alo_ + (long)h * aStrH;
  }
  const u16* Bhi = Bhi_ + (long)h * bStrH;
  const u16* Blo = nullptr;
  if constexpr (SPLIT) Blo = Blo_ + (long)h * bStrH;

  f32x4 acc[4][4];
#pragma unroll
  for (int i = 0; i < 4; i++)
#pragma unroll
    for (int j = 0; j < 4; j++) acc[i][j] = (f32x4)0.0f;

  for (int k0 = 0; k0 < Kdim; k0 += BK) {
    // ---- stage A ----
    if constexpr (AF32) {
      constexpr int FR = (128 * BK) / (256 * 4);
#pragma unroll
      for (int r = 0; r < FR; ++r) {
        int e = (r * 256 + tid) * 4;
        int row = e / BK, col = e % BK;
        long gi = (bm + row) * (long)lda + k0 + col;
        float4 v = *(const float4*)(Af32 + gi);
        float iv = invRow[bm + row];
        v.x *= iv; v.y *= iv; v.z *= iv; v.w *= iv;
        *(float4*)(Awb + gi) = v;  // final normalized attn output
        ushort4 b = make_ushort4(f2bf(v.x), f2bf(v.y), f2bf(v.z), f2bf(v.w));
        *(ushort4*)(&sAhi[row * BK + col]) = b;
      }
    } else {
      constexpr int GR = (128 * BK) / (256 * 8);
#pragma unroll
      for (int r = 0; r < GR; ++r) {
        int e = (r * 256 + tid) * 8;
        int row = e / BK, col = e % BK;
        long gi = (bm + row) * (long)lda + k0 + col;
        g2l16(Ahi + gi, (char*)sAhi + (size_t)e * 2);
        if constexpr (SPLIT) g2l16(Alo + gi, (char*)sAlo + (size_t)e * 2);
      }
    }
    // ---- stage B ----
    {
      constexpr int GR = (128 * BK) / (256 * 8);
#pragma unroll
      for (int r = 0; r < GR; ++r) {
        int e = (r * 256 + tid) * 8;
        int row = e / BK, col = e % BK;
        long gi = (bn + row) * (long)ldb + k0 + col;
        g2l16(Bhi + gi, (char*)sBhi + (size_t)e * 2);
        if constexpr (SPLIT) g2l16(Blo + gi, (char*)sBlo + (size_t)e * 2);
      }
    }
    __syncthreads();

#pragma unroll
    for (int ks = 0; ks < BK; ks += 32) {
      bf16x8 aH[4], bH[4];
      bf16x8 aL[SPLIT ? 4 : 1], bL[SPLIT ? 4 : 1];
#pragma unroll
      for (int mi = 0; mi < 4; mi++) {
        int m = wr * 64 + mi * 16 + l16;
        int off = m * BK + ks + quad * 8;
        aH[mi] = *(const bf16x8*)&sAhi[off];
        if constexpr (SPLIT) aL[mi] = *(const bf16x8*)&sAlo[off];
      }
#pragma unroll
      for (int ni = 0; ni < 4; ni++) {
        int n = wc * 64 + ni * 16 + l16;
        int off = n * BK + ks + quad * 8;
        bH[ni] = *(const bf16x8*)&sBhi[off];
        if constexpr (SPLIT) bL[ni] = *(const bf16x8*)&sBlo[off];
      }
#pragma unroll
      for (int mi = 0; mi < 4; mi++)
#pragma unroll
        for (int ni = 0; ni < 4; ni++) {
          acc[mi][ni] = __builtin_amdgcn_mfma_f32_16x16x32_bf16(aH[mi], bH[ni], acc[mi][ni], 0, 0, 0);
          if constexpr (SPLIT) {
            acc[mi][ni] = __builtin_amdgcn_mfma_f32_16x16x32_bf16(aH[mi], bL[ni], acc[mi][ni], 0, 0, 0);
            acc[mi][ni] = __builtin_amdgcn_mfma_f32_16x16x32_bf16(aL[mi], bH[ni], acc[mi][ni], 0, 0, 0);
          }
        }
    }
    __syncthreads();
  }

  // ---- epilogue ----
  const long rowB = bm + wr * 64;
  const long colB = bn + wc * 64;
  if constexpr (EPI == 3) {
    float* C = (float*)C0 + (long)h * cStrH;
    float* rowSum = rowSum_ + (long)h * rStrH;
#pragma unroll
    for (int mi = 0; mi < 4; mi++) {
      f32x4 rs = (f32x4)0.0f;
#pragma unroll
      for (int ni = 0; ni < 4; ni++) {
        long col = colB + ni * 16 + l16;
#pragma unroll
        for (int r = 0; r < 4; r++) {
          long row = rowB + mi * 16 + quad * 4 + r;
          float e = __expf(acc[mi][ni][r] * scale);
          C[row * (long)ldc + col] = e;
          rs[r] += e;
        }
      }
#pragma unroll
      for (int m = 1; m < 16; m <<= 1) {
        rs[0] += __shfl_xor(rs[0], m);
        rs[1] += __shfl_xor(rs[1], m);
        rs[2] += __shfl_xor(rs[2], m);
        rs[3] += __shfl_xor(rs[3], m);
      }
      if (l16 == 0) {
#pragma unroll
        for (int r = 0; r < 4; r++)
          atomicAdd(&rowSum[rowB + mi * 16 + quad * 4 + r], rs[r]);
      }
    }
  } else if constexpr (EPI == 2) {
    u16* Chi = (u16*)C0;
    u16* Clo = (u16*)C1;
#pragma unroll
    for (int mi = 0; mi < 4; mi++)
#pragma unroll
      for (int ni = 0; ni < 4; ni++) {
        long col = colB + ni * 16 + l16;
#pragma unroll
        for (int r = 0; r < 4; r++) {
          long idx = (rowB + mi * 16 + quad * 4 + r) * (long)ldc + col;
          float v = acc[mi][ni][r];
          u16 hi = f2bf(v);
          Chi[idx] = hi;
          Clo[idx] = f2bf(v - bf2f(hi));
        }
      }
  } else if constexpr (EPI == 1) {
    u16* C = (u16*)C0 + (long)h * cStrH;
#pragma unroll
    for (int mi = 0; mi < 4; mi++)
#pragma unroll
      for (int ni = 0; ni < 4; ni++) {
        long col = colB + ni * 16 + l16;
#pragma unroll
        for (int r = 0; r < 4; r++) {
          long idx = (rowB + mi * 16 + quad * 4 + r) * (long)ldc + col;
          C[idx] = f2bf(acc[mi][ni][r]);
        }
      }
  } else {
    float* C = (float*)C0 + (long)h * cStrH;
#pragma unroll
    for (int mi = 0; mi < 4; mi++)
#pragma unroll
      for (int ni = 0; ni < 4; ni++) {
        long col = colB + ni * 16 + l16;
#pragma unroll
        for (int r = 0; r < 4; r++) {
          long idx = (rowB + mi * 16 + quad * 4 + r) * (long)ldc + col;
          C[idx] = acc[mi][ni][r];
        }
      }
  }
}

// ---------------------------------------------------------------- launcher

extern "C" void kernel_launch(void* const* d_in, const int* in_sizes, int n_in,
                              void* d_out, int out_size, void* d_ws, size_t ws_size,
                              hipStream_t stream) {
  const float* x = (const float*)d_in[0];
  const float* Wq = (const float*)d_in[1];
  const float* Wk = (const float*)d_in[2];
  const float* Wv = (const float*)d_in[3];
  const float* Wo = (const float*)d_in[4];

  float* outY = (float*)d_out;                 // 4096*1024
  float* attn = outY + (size_t)SEQ * FDIM;     // 8*4096*4096 (also exp scratch)

  // workspace carve-up (u16 elements)
  u16* ws = (u16*)d_ws;
  const size_t NX = (size_t)SEQ * FDIM;   // 4194304
  const size_t NW = (size_t)FDIM * FDIM;  // 1048576
  u16* xhi = ws;
  u16* xlo = xhi + NX;
  u16* wqt_h = xlo + NX;
  u16* wqt_l = wqt_h + NW;
  u16* wkt_h = wqt_l + NW;
  u16* wkt_l = wkt_h + NW;
  u16* wvt = wkt_l + NW;
  u16* wot = wvt + NW;
  u16* Qhi = wot + NW;
  u16* Qlo = Qhi + NX;
  u16* Khi = Qlo + NX;
  u16* Klo = Khi + NX;
  u16* Vb = Klo + NX;
  u16* Vt = Vb + NX;
  u16* Yb = Vt + NX;
  float* rowSum = (float*)(Yb + NX);
  float* invRow = rowSum + (size_t)NHEAD * SEQ;
  // total ~88.4 MB of ws

  hipMemsetAsync(rowSum, 0, (size_t)NHEAD * SEQ * sizeof(float), stream);

  split_f32_bf16<<<dim3((NX / 4 + 255) / 256), 256, 0, stream>>>((const float4*)x, xhi, xlo, NX / 4);

  dim3 tb(32, 8);
  transpose_split_w<<<dim3(32, 32), tb, 0, stream>>>(Wq, wqt_h, wqt_l, FDIM, 1);
  transpose_split_w<<<dim3(32, 32), tb, 0, stream>>>(Wk, wkt_h, wkt_l, FDIM, 1);
  transpose_split_w<<<dim3(32, 32), tb, 0, stream>>>(Wv, wvt, nullptr, FDIM, 0);
  transpose_split_w<<<dim3(32, 32), tb, 0, stream>>>(Wo, wot, nullptr, FDIM, 0);

  // Q = x@Wq, K = x@Wk  (split path, split output)
  gemm_bt<32, true, false, 2><<<dim3(8, 32, 1), 256, 0, stream>>>(
      xhi, xlo, nullptr, nullptr, nullptr, wqt_h, wqt_l,
      Qhi, Qlo, nullptr, 1024, 1024, 1024, 1024, 0, 0, 0, 0, 0.f);
  gemm_bt<32, true, false, 2><<<dim3(8, 32, 1), 256, 0, stream>>>(
      xhi, xlo, nullptr, nullptr, nullptr, wkt_h, wkt_l,
      Khi, Klo, nullptr, 1024, 1024, 1024, 1024, 0, 0, 0, 0, 0.f);
  // V = x@Wv (plain bf16)
  gemm_bt<64, false, false, 1><<<dim3(8, 32, 1), 256, 0, stream>>>(
      xhi, nullptr, nullptr, nullptr, nullptr, wvt, nullptr,
      Vb, nullptr, nullptr, 1024, 1024, 1024, 1024, 0, 0, 0, 0, 0.f);
  transpose_bf16<<<dim3(32, 128), tb, 0, stream>>>(Vb, Vt, SEQ, FDIM);

  // expS = exp(Q K^T / sqrt(dk)) into attn region + rowsums
  gemm_bt<32, true, false, 3><<<dim3(32, 32, NHEAD), 256, 0, stream>>>(
      Qhi, Qlo, nullptr, nullptr, nullptr, Khi, Klo,
      attn, nullptr, rowSum, 128, 1024, 1024, 4096,
      128, 128, (long)SEQ * SEQ, SEQ, 0.08838834764831845f);

  reciprocal_k<<<(NHEAD * SEQ + 255) / 256, 256, 0, stream>>>(rowSum, invRow, NHEAD * SEQ);

  // y = attn @ V  (normalize attn in-place while staging)
  gemm_bt<64, false, true, 1><<<dim3(1, 32, NHEAD), 256, 0, stream>>>(
      nullptr, nullptr, attn, attn, invRow, Vt, nullptr,
      Yb, nullptr, nullptr, 4096, 4096, 4096, 1024,
      (long)SEQ * SEQ, (long)128 * SEQ, 128, SEQ, 0.f);

  // out = y @ Wo
  gemm_bt<64, false, false, 0><<<dim3(8, 32, 1), 256, 0, stream>>>(
      Yb, nullptr, nullptr, nullptr, nullptr, wot, nullptr,
      outY, nullptr, nullptr, 1024, 1024, 1024, 1024, 0, 0, 0, 0, 0.f);
}

// Round 2
// 1063.990 us; speedup vs baseline: 1.2565x; 1.2565x over previous
//
#include <hip/hip_runtime.h>
#include <math.h>

// MultiHeadAttention: x[1,4096,1024] fp32, Wq/Wk/Wv[1024,1024], Wo[1024,1024].
// Outputs (concat in d_out): y[4096*1024] fp32, attn[8*4096*4096] fp32.
//
// R2 structure:
//   split x / transpose weights -> Q,K proj (split-bf16, fused z=2 launch),
//   V proj + transpose -> qk_exp (split QK, exp, bf16 store + rowsums) ->
//   reciprocal -> pv_norm (normalize+write final fp32 attn while staging,
//   y_un = P@V via MFMA) -> Wo proj.
// expS bf16 scratch (268 MB) lives in ws if it fits, else fp32 in-place in
// the attn output region (template fallback).

typedef unsigned short u16;
typedef __attribute__((ext_vector_type(8))) short bf16x8;
typedef __attribute__((ext_vector_type(4))) float f32x4;

#define SEQ 4096
#define FDIM 1024
#define NHEAD 8
#define DK 128

__device__ __forceinline__ u16 f2bf(float f) {
  unsigned u = __float_as_uint(f);
  u += 0x7fffu + ((u >> 16) & 1u);  // round-to-nearest-even
  return (u16)(u >> 16);
}
__device__ __forceinline__ float bf2f(u16 h) {
  return __uint_as_float(((unsigned)h) << 16);
}

__device__ __forceinline__ void g2l16(const void* g, void* l) {
  __builtin_amdgcn_global_load_lds(
      (const __attribute__((address_space(1))) void*)g,
      (__attribute__((address_space(3))) void*)l, 16, 0, 0);
}

// ---------------------------------------------------------------- prep kernels

__global__ void split_f32_bf16(const float4* __restrict__ in, u16* __restrict__ ohi,
                               u16* __restrict__ olo, int n4) {
  int i = blockIdx.x * 256 + threadIdx.x;
  if (i >= n4) return;
  float4 v = in[i];
  u16 h0 = f2bf(v.x), h1 = f2bf(v.y), h2 = f2bf(v.z), h3 = f2bf(v.w);
  u16 l0 = f2bf(v.x - bf2f(h0)), l1 = f2bf(v.y - bf2f(h1));
  u16 l2 = f2bf(v.z - bf2f(h2)), l3 = f2bf(v.w - bf2f(h3));
  *(ushort4*)(ohi + 4 * (size_t)i) = make_ushort4(h0, h1, h2, h3);
  *(ushort4*)(olo + 4 * (size_t)i) = make_ushort4(l0, l1, l2, l3);
}

// out[n][k] = in[k][n], 1024x1024, optional split
__global__ void transpose_split_w(const float* __restrict__ in, u16* __restrict__ ohi,
                                  u16* __restrict__ olo, int dim, int do_split) {
  __shared__ float t[32][33];
  int tx = threadIdx.x, ty = threadIdx.y;
  int x = blockIdx.x * 32 + tx;
  int y0 = blockIdx.y * 32;
  for (int j = ty; j < 32; j += 8) t[j][tx] = in[(long)(y0 + j) * dim + x];
  __syncthreads();
  int x2 = y0 + tx;
  int y2 = blockIdx.x * 32;
  for (int j = ty; j < 32; j += 8) {
    float v = t[tx][j];
    u16 hi = f2bf(v);
    ohi[(long)(y2 + j) * dim + x2] = hi;
    if (do_split) olo[(long)(y2 + j) * dim + x2] = f2bf(v - bf2f(hi));
  }
}

__global__ void transpose_bf16(const u16* __restrict__ in, u16* __restrict__ out,
                               int rows, int cols) {
  __shared__ u16 t[32][33];
  int tx = threadIdx.x, ty = threadIdx.y;
  int x = blockIdx.x * 32 + tx;
  int y0 = blockIdx.y * 32;
  for (int j = ty; j < 32; j += 8) t[j][tx] = in[(long)(y0 + j) * cols + x];
  __syncthreads();
  int x2 = y0 + tx;
  int y2 = blockIdx.x * 32;
  for (int j = ty; j < 32; j += 8) out[(long)(y2 + j) * rows + x2] = t[tx][j];
}

__global__ void reciprocal_k(const float* __restrict__ in, float* __restrict__ out, int n) {
  int i = blockIdx.x * 256 + threadIdx.x;
  if (i < n) out[i] = 1.0f / in[i];
}

// ---------------------------------------------------------------- projection GEMM (C = A * B^T)
// EPI: 0 = fp32 store, 1 = bf16 store, 2 = split bf16 store
template <int BK, bool SPLIT, int EPI>
__global__ __launch_bounds__(256, 2) void gemm_bt(
    const u16* Ahi_, const u16* Alo_,
    const u16* Bhi_, const u16* Blo_,
    void* C0, void* C1,
    int Kdim, int lda, int ldb, int ldc,
    long aStrH, long bStrH, long cStrH) {
  constexpr int LDSN = 128 * BK;
  __shared__ u16 sAhi[LDSN];
  __shared__ u16 sBhi[LDSN];
  __shared__ u16 sAlo[SPLIT ? LDSN : 2];
  __shared__ u16 sBlo[SPLIT ? LDSN : 2];

  const int tid = threadIdx.x;
  const int lane = tid & 63;
  const int wave = tid >> 6;
  const int wr = wave >> 1, wc = wave & 1;
  const int quad = lane >> 4, l16 = lane & 15;
  const int h = blockIdx.z;
  const long bm = (long)blockIdx.y * 128;
  const long bn = (long)blockIdx.x * 128;

  const u16* Ahi = Ahi_ + (long)h * aStrH;
  const u16* Alo = SPLIT ? (Alo_ + (long)h * aStrH) : nullptr;
  const u16* Bhi = Bhi_ + (long)h * bStrH;
  const u16* Blo = SPLIT ? (Blo_ + (long)h * bStrH) : nullptr;

  f32x4 acc[4][4];
#pragma unroll
  for (int i = 0; i < 4; i++)
#pragma unroll
    for (int j = 0; j < 4; j++) acc[i][j] = (f32x4)0.0f;

  for (int k0 = 0; k0 < Kdim; k0 += BK) {
    constexpr int GR = (128 * BK) / (256 * 8);
#pragma unroll
    for (int r = 0; r < GR; ++r) {
      int e = (r * 256 + tid) * 8;
      int row = e / BK, col = e % BK;
      long ga = (bm + row) * (long)lda + k0 + col;
      long gb = (bn + row) * (long)ldb + k0 + col;
      g2l16(Ahi + ga, (char*)sAhi + (size_t)e * 2);
      g2l16(Bhi + gb, (char*)sBhi + (size_t)e * 2);
      if constexpr (SPLIT) {
        g2l16(Alo + ga, (char*)sAlo + (size_t)e * 2);
        g2l16(Blo + gb, (char*)sBlo + (size_t)e * 2);
      }
    }
    __syncthreads();

#pragma unroll
    for (int ks = 0; ks < BK; ks += 32) {
      bf16x8 aH[4], bH[4];
      bf16x8 aL[SPLIT ? 4 : 1], bL[SPLIT ? 4 : 1];
#pragma unroll
      for (int mi = 0; mi < 4; mi++) {
        int off = (wr * 64 + mi * 16 + l16) * BK + ks + quad * 8;
        aH[mi] = *(const bf16x8*)&sAhi[off];
        if constexpr (SPLIT) aL[mi] = *(const bf16x8*)&sAlo[off];
      }
#pragma unroll
      for (int ni = 0; ni < 4; ni++) {
        int off = (wc * 64 + ni * 16 + l16) * BK + ks + quad * 8;
        bH[ni] = *(const bf16x8*)&sBhi[off];
        if constexpr (SPLIT) bL[ni] = *(const bf16x8*)&sBlo[off];
      }
#pragma unroll
      for (int mi = 0; mi < 4; mi++)
#pragma unroll
        for (int ni = 0; ni < 4; ni++) {
          acc[mi][ni] = __builtin_amdgcn_mfma_f32_16x16x32_bf16(aH[mi], bH[ni], acc[mi][ni], 0, 0, 0);
          if constexpr (SPLIT) {
            acc[mi][ni] = __builtin_amdgcn_mfma_f32_16x16x32_bf16(aH[mi], bL[ni], acc[mi][ni], 0, 0, 0);
            acc[mi][ni] = __builtin_amdgcn_mfma_f32_16x16x32_bf16(aL[mi], bH[ni], acc[mi][ni], 0, 0, 0);
          }
        }
    }
    __syncthreads();
  }

  const long rowB = bm + wr * 64;
  const long colB = bn + wc * 64;
  if constexpr (EPI == 2) {
    u16* Chi = (u16*)C0 + (long)h * cStrH;
    u16* Clo = (u16*)C1 + (long)h * cStrH;
#pragma unroll
    for (int mi = 0; mi < 4; mi++)
#pragma unroll
      for (int ni = 0; ni < 4; ni++) {
        long col = colB + ni * 16 + l16;
#pragma unroll
        for (int r = 0; r < 4; r++) {
          long idx = (rowB + mi * 16 + quad * 4 + r) * (long)ldc + col;
          float v = acc[mi][ni][r];
          u16 hi = f2bf(v);
          Chi[idx] = hi;
          Clo[idx] = f2bf(v - bf2f(hi));
        }
      }
  } else if constexpr (EPI == 1) {
    u16* C = (u16*)C0 + (long)h * cStrH;
#pragma unroll
    for (int mi = 0; mi < 4; mi++)
#pragma unroll
      for (int ni = 0; ni < 4; ni++) {
        long col = colB + ni * 16 + l16;
#pragma unroll
        for (int r = 0; r < 4; r++)
          C[(rowB + mi * 16 + quad * 4 + r) * (long)ldc + col] = f2bf(acc[mi][ni][r]);
      }
  } else {
    float* C = (float*)C0 + (long)h * cStrH;
#pragma unroll
    for (int mi = 0; mi < 4; mi++)
#pragma unroll
      for (int ni = 0; ni < 4; ni++) {
        long col = colB + ni * 16 + l16;
#pragma unroll
        for (int r = 0; r < 4; r++)
          C[(rowB + mi * 16 + quad * 4 + r) * (long)ldc + col] = acc[mi][ni][r];
      }
  }
}

// ---------------------------------------------------------------- QK^T + exp
// S = exp(scale * Q K^T) per head; stores bf16 (or fp32 fallback) + rowsums.
// Q,K: [4096][1024] split bf16; head h = cols [h*128, h*128+128).
template <bool BF16S>
__global__ __launch_bounds__(256, 2) void qk_exp(
    const u16* __restrict__ Qhi, const u16* __restrict__ Qlo,
    const u16* __restrict__ Khi, const u16* __restrict__ Klo,
    void* __restrict__ outE, float* __restrict__ rowSum, float scale) {
  __shared__ u16 smem[32768];  // 64 KB: staging; first 32 KB reused as P-buf
  u16* sQh = smem;
  u16* sQl = smem + 8192;
  u16* sKh = smem + 16384;
  u16* sKl = smem + 24576;

  const int tid = threadIdx.x;
  const int lane = tid & 63, wave = tid >> 6;
  const int wr = wave >> 1, wc = wave & 1;
  const int quad = lane >> 4, l16 = lane & 15;
  const int h = blockIdx.z;
  const int bm = blockIdx.y * 128, bn = blockIdx.x * 128;
  const int colOff = h * DK;

  f32x4 acc[4][4];
#pragma unroll
  for (int i = 0; i < 4; i++)
#pragma unroll
    for (int j = 0; j < 4; j++) acc[i][j] = (f32x4)0.0f;

  for (int k0 = 0; k0 < DK; k0 += 64) {
#pragma unroll
    for (int r = 0; r < 4; ++r) {
      int e = (r * 256 + tid) * 8;
      int row = e >> 6, col = e & 63;
      long gq = (long)(bm + row) * FDIM + colOff + k0 + col;
      long gk = (long)(bn + row) * FDIM + colOff + k0 + col;
      g2l16(Qhi + gq, (char*)sQh + (size_t)e * 2);
      g2l16(Qlo + gq, (char*)sQl + (size_t)e * 2);
      g2l16(Khi + gk, (char*)sKh + (size_t)e * 2);
      g2l16(Klo + gk, (char*)sKl + (size_t)e * 2);
    }
    __syncthreads();
#pragma unroll
    for (int ks = 0; ks < 64; ks += 32) {
      bf16x8 aH[4], aL[4], bH[4], bL[4];
#pragma unroll
      for (int i = 0; i < 4; i++) {
        int offA = (wr * 64 + i * 16 + l16) * 64 + ks + quad * 8;
        int offB = (wc * 64 + i * 16 + l16) * 64 + ks + quad * 8;
        aH[i] = *(const bf16x8*)&sQh[offA];
        aL[i] = *(const bf16x8*)&sQl[offA];
        bH[i] = *(const bf16x8*)&sKh[offB];
        bL[i] = *(const bf16x8*)&sKl[offB];
      }
#pragma unroll
      for (int mi = 0; mi < 4; mi++)
#pragma unroll
        for (int ni = 0; ni < 4; ni++) {
          acc[mi][ni] = __builtin_amdgcn_mfma_f32_16x16x32_bf16(aH[mi], bH[ni], acc[mi][ni], 0, 0, 0);
          acc[mi][ni] = __builtin_amdgcn_mfma_f32_16x16x32_bf16(aH[mi], bL[ni], acc[mi][ni], 0, 0, 0);
          acc[mi][ni] = __builtin_amdgcn_mfma_f32_16x16x32_bf16(aL[mi], bH[ni], acc[mi][ni], 0, 0, 0);
        }
    }
    __syncthreads();
  }

  // exp in place + per-row sums (shfl over the 16 col-lanes, atomic per block)
#pragma unroll
  for (int mi = 0; mi < 4; mi++) {
    f32x4 rs = (f32x4)0.0f;
#pragma unroll
    for (int ni = 0; ni < 4; ni++)
#pragma unroll
      for (int r = 0; r < 4; r++) {
        float e = __expf(acc[mi][ni][r] * scale);
        acc[mi][ni][r] = e;
        rs[r] += e;
      }
#pragma unroll
    for (int m = 1; m < 16; m <<= 1) {
      rs[0] += __shfl_xor(rs[0], m);
      rs[1] += __shfl_xor(rs[1], m);
      rs[2] += __shfl_xor(rs[2], m);
      rs[3] += __shfl_xor(rs[3], m);
    }
    if (l16 == 0) {
      int rbase = h * SEQ + bm + wr * 64 + mi * 16 + quad * 4;
#pragma unroll
      for (int r = 0; r < 4; r++) atomicAdd(&rowSum[rbase + r], rs[r]);
    }
  }

  // transpose tile through LDS for vectorized stores
  u16* P = smem;  // 128x128 bf16 = 32 KB (staging no longer needed)
#pragma unroll
  for (int mi = 0; mi < 4; mi++)
#pragma unroll
    for (int ni = 0; ni < 4; ni++)
#pragma unroll
      for (int r = 0; r < 4; r++)
        P[(wr * 64 + mi * 16 + quad * 4 + r) * 128 + wc * 64 + ni * 16 + l16] =
            f2bf(acc[mi][ni][r]);
  __syncthreads();

  if constexpr (BF16S) {
    u16* out = (u16*)outE + ((long)h << 24);
#pragma unroll
    for (int j = 0; j < 8; ++j) {
      int e = (j * 256 + tid) * 8;
      int row = e >> 7, col = e & 127;
      long g = (long)(bm + row) * SEQ + bn + col;
      *(uint4*)(out + g) = *(const uint4*)(P + e);
    }
  } else {
    float* out = (float*)outE + ((long)h << 24);
#pragma unroll
    for (int j = 0; j < 16; ++j) {
      int e = (j * 256 + tid) * 4;
      int row = e >> 7, col = e & 127;
      long g = (long)(bm + row) * SEQ + bn + col;
      ushort4 u = *(const ushort4*)(P + e);
      *(float4*)(out + g) = make_float4(bf2f(u.x), bf2f(u.y), bf2f(u.z), bf2f(u.w));
    }
  }
}

// ---------------------------------------------------------------- PV + attn normalize
// Reads expS, multiplies by invRow in staging, writes final fp32 attn, and
// computes y = P_norm @ V via MFMA (Vt = V^T [1024][4096]). 64-row blocks.
template <bool BF16S>
__global__ __launch_bounds__(256, 2) void pv_norm(
    const void* __restrict__ expS, const float* __restrict__ invRow,
    float* __restrict__ attnOut, const u16* __restrict__ Vt,
    u16* __restrict__ Yb) {
  __shared__ u16 sP[64 * 64];   // 8 KB
  __shared__ u16 sV[128 * 64];  // 16 KB
  const int tid = threadIdx.x;
  const int lane = tid & 63, wave = tid >> 6;
  const int wr = wave >> 1, wc = wave & 1;
  const int quad = lane >> 4, l16 = lane & 15;
  const int h = blockIdx.z;
  const int bm = blockIdx.y * 64;

  f32x4 acc[2][4];
#pragma unroll
  for (int i = 0; i < 2; i++)
#pragma unroll
    for (int j = 0; j < 4; j++) acc[i][j] = (f32x4)0.0f;

  for (int k0 = 0; k0 < SEQ; k0 += 64) {
#pragma unroll
    for (int c = 0; c < 2; ++c) {
      int e = (c * 256 + tid) * 8;
      int row = e >> 6, col = e & 63;
      long arow = (long)h * SEQ + bm + row;
      long g = arow * SEQ + k0 + col;
      float inv = invRow[arow];
      float p[8];
      if constexpr (BF16S) {
        ushort4 u0 = *(const ushort4*)((const u16*)expS + g);
        ushort4 u1 = *(const ushort4*)((const u16*)expS + g + 4);
        p[0] = bf2f(u0.x) * inv; p[1] = bf2f(u0.y) * inv;
        p[2] = bf2f(u0.z) * inv; p[3] = bf2f(u0.w) * inv;
        p[4] = bf2f(u1.x) * inv; p[5] = bf2f(u1.y) * inv;
        p[6] = bf2f(u1.z) * inv; p[7] = bf2f(u1.w) * inv;
      } else {
        float4 f0 = *(const float4*)((const float*)expS + g);
        float4 f1 = *(const float4*)((const float*)expS + g + 4);
        p[0] = f0.x * inv; p[1] = f0.y * inv; p[2] = f0.z * inv; p[3] = f0.w * inv;
        p[4] = f1.x * inv; p[5] = f1.y * inv; p[6] = f1.z * inv; p[7] = f1.w * inv;
      }
      *(float4*)(attnOut + g) = make_float4(p[0], p[1], p[2], p[3]);
      *(float4*)(attnOut + g + 4) = make_float4(p[4], p[5], p[6], p[7]);
      *(ushort4*)(sP + e) = make_ushort4(f2bf(p[0]), f2bf(p[1]), f2bf(p[2]), f2bf(p[3]));
      *(ushort4*)(sP + e + 4) = make_ushort4(f2bf(p[4]), f2bf(p[5]), f2bf(p[6]), f2bf(p[7]));
    }
#pragma unroll
    for (int r = 0; r < 4; ++r) {
      int e = (r * 256 + tid) * 8;
      int row = e >> 6, col = e & 63;
      g2l16(Vt + (long)(h * DK + row) * SEQ + k0 + col, (char*)sV + (size_t)e * 2);
    }
    __syncthreads();
#pragma unroll
    for (int ks = 0; ks < 64; ks += 32) {
      bf16x8 a[2], b[4];
#pragma unroll
      for (int i = 0; i < 2; i++)
        a[i] = *(const bf16x8*)&sP[(wr * 32 + i * 16 + l16) * 64 + ks + quad * 8];
#pragma unroll
      for (int i = 0; i < 4; i++)
        b[i] = *(const bf16x8*)&sV[(wc * 64 + i * 16 + l16) * 64 + ks + quad * 8];
#pragma unroll
      for (int mi = 0; mi < 2; mi++)
#pragma unroll
        for (int ni = 0; ni < 4; ni++)
          acc[mi][ni] = __builtin_amdgcn_mfma_f32_16x16x32_bf16(a[mi], b[ni], acc[mi][ni], 0, 0, 0);
    }
    __syncthreads();
  }

#pragma unroll
  for (int mi = 0; mi < 2; mi++)
#pragma unroll
    for (int ni = 0; ni < 4; ni++)
#pragma unroll
      for (int r = 0; r < 4; r++) {
        long row = bm + wr * 32 + mi * 16 + quad * 4 + r;
        int col = h * DK + wc * 64 + ni * 16 + l16;
        Yb[row * (long)FDIM + col] = f2bf(acc[mi][ni][r]);
      }
}

// ---------------------------------------------------------------- launcher

extern "C" void kernel_launch(void* const* d_in, const int* in_sizes, int n_in,
                              void* d_out, int out_size, void* d_ws, size_t ws_size,
                              hipStream_t stream) {
  const float* x = (const float*)d_in[0];
  const float* Wq = (const float*)d_in[1];
  const float* Wk = (const float*)d_in[2];
  const float* Wv = (const float*)d_in[3];
  const float* Wo = (const float*)d_in[4];

  float* outY = (float*)d_out;              // 4096*1024
  float* attn = outY + (size_t)SEQ * FDIM;  // 8*4096*4096

  const size_t NX = (size_t)SEQ * FDIM;   // 4194304
  const size_t NW = (size_t)FDIM * FDIM;  // 1048576

  u16* p = (u16*)d_ws;
  u16* xhi = p; p += NX;
  u16* xlo = p; p += NX;
  u16* wqt_h = p; p += NW;
  u16* wqt_l = p; p += NW;
  u16* wkt_h = p; p += NW;   // wqt_h + 2*NW (z-stride for fused QK proj)
  u16* wkt_l = p; p += NW;
  u16* wvt = p; p += NW;
  u16* wot = p; p += NW;
  u16* Qhi = p; p += NX;
  u16* Qlo = p; p += NX;
  u16* Khi = p; p += NX;     // Qhi + 2*NX
  u16* Klo = p; p += NX;
  u16* Vb = p; p += NX;
  u16* Vt = p; p += NX;
  u16* Yb = p; p += NX;
  float* rowSum = (float*)p;
  float* invRow = rowSum + (size_t)NHEAD * SEQ;
  u16* expS = (u16*)(invRow + (size_t)NHEAD * SEQ);
  size_t need = (size_t)((char*)(expS + (size_t)NHEAD * SEQ * SEQ) - (char*)d_ws);
  bool bf16s = ws_size >= need;

  hipMemsetAsync(rowSum, 0, (size_t)NHEAD * SEQ * sizeof(float), stream);

  split_f32_bf16<<<dim3((NX / 4 + 255) / 256), 256, 0, stream>>>(
      (const float4*)x, xhi, xlo, NX / 4);

  dim3 tb(32, 8);
  transpose_split_w<<<dim3(32, 32), tb, 0, stream>>>(Wq, wqt_h, wqt_l, FDIM, 1);
  transpose_split_w<<<dim3(32, 32), tb, 0, stream>>>(Wk, wkt_h, wkt_l, FDIM, 1);
  transpose_split_w<<<dim3(32, 32), tb, 0, stream>>>(Wv, wvt, nullptr, FDIM, 0);
  transpose_split_w<<<dim3(32, 32), tb, 0, stream>>>(Wo, wot, nullptr, FDIM, 0);

  // Q and K projections fused (z=0 -> Q, z=1 -> K), split in/out
  gemm_bt<32, true, 2><<<dim3(8, 32, 2), 256, 0, stream>>>(
      xhi, xlo, wqt_h, wqt_l, Qhi, Qlo,
      1024, 1024, 1024, 1024, 0, (long)2 * NW, (long)2 * NX);

  // V projection (plain bf16) + transpose
  gemm_bt<64, false, 1><<<dim3(8, 32, 1), 256, 0, stream>>>(
      xhi, nullptr, wvt, nullptr, Vb, nullptr,
      1024, 1024, 1024, 1024, 0, 0, 0);
  transpose_bf16<<<dim3(32, 128), tb, 0, stream>>>(Vb, Vt, SEQ, FDIM);

  const float scale = 0.08838834764831845f;  // 1/sqrt(128)
  if (bf16s) {
    qk_exp<true><<<dim3(32, 32, NHEAD), 256, 0, stream>>>(
        Qhi, Qlo, Khi, Klo, expS, rowSum, scale);
  } else {
    qk_exp<false><<<dim3(32, 32, NHEAD), 256, 0, stream>>>(
        Qhi, Qlo, Khi, Klo, attn, rowSum, scale);
  }

  reciprocal_k<<<(NHEAD * SEQ + 255) / 256, 256, 0, stream>>>(rowSum, invRow, NHEAD * SEQ);

  if (bf16s) {
    pv_norm<true><<<dim3(1, 64, NHEAD), 256, 0, stream>>>(expS, invRow, attn, Vt, Yb);
  } else {
    pv_norm<false><<<dim3(1, 64, NHEAD), 256, 0, stream>>>(attn, invRow, attn, Vt, Yb);
  }

  // out = y @ Wo
  gemm_bt<64, false, 0><<<dim3(8, 32, 1), 256, 0, stream>>>(
      Yb, nullptr, wot, nullptr, outY, nullptr,
      1024, 1024, 1024, 1024, 0, 0, 0);
}